// Round 1
// baseline (617.971 us; speedup 1.0000x reference)
//
#include <hip/hip_runtime.h>
#include <math.h>

namespace {

constexpr int kHid = 512;
constexpr int kRank = 4;
constexpr int kIn = 3;
constexpr int kOut = 3;
constexpr int kBatch = 128;
constexpr int kSeq = 1000;
constexpr float kNoiseStd = 0.05f;
constexpr float kTau = 0.2f;
constexpr int kBlock = 256;  // 4 waves, 2 h per thread

template <int CTRL, int RMASK>
__device__ __forceinline__ float dpp_add(float x) {
  int s = __builtin_amdgcn_update_dpp(0, __float_as_int(x), CTRL, RMASK, 0xF, true);
  return x + __int_as_float(s);
}

// After this, lane 63 of the wave holds the 64-lane sum (LLVM gfx9 pattern).
__device__ __forceinline__ float wave_sum63(float x) {
  x = dpp_add<0xB1, 0xF>(x);   // quad_perm [1,0,3,2]  (xor 1)
  x = dpp_add<0x4E, 0xF>(x);   // quad_perm [2,3,0,1]  (xor 2)
  x = dpp_add<0x141, 0xF>(x);  // row_half_mirror      (xor 4-ish)
  x = dpp_add<0x140, 0xF>(x);  // row_mirror           (xor 8-ish)
  x = dpp_add<0x142, 0xA>(x);  // row_bcast15 -> rows 1,3
  x = dpp_add<0x143, 0xC>(x);  // row_bcast31 -> rows 2,3
  return x;
}

__device__ __forceinline__ float quad_sum(float x) {
  x = dpp_add<0xB1, 0xF>(x);
  x = dpp_add<0x4E, 0xF>(x);
  return x;  // all 4 lanes of the quad hold the quad sum
}

__device__ __forceinline__ float tanh_fast(float x) {
  float e = __expf(2.0f * x);  // v_mul + v_exp_f32
  return fmaf(-2.0f, __builtin_amdgcn_rcpf(e + 1.0f), 1.0f);
}

__global__ __launch_bounds__(kBlock) void rnn_fused(
    const float* __restrict__ u, const float* __restrict__ x0,
    const float* __restrict__ noise, const float* __restrict__ Lw,
    const float* __restrict__ Mw, const float* __restrict__ Nw,
    const float* __restrict__ bias, const float* __restrict__ Win,
    const float* __restrict__ Wout, float* __restrict__ out,
    float* __restrict__ xfinal, float* __restrict__ traj) {
  const int b = blockIdx.x;
  const int tid = threadIdx.x;
  const int lane = tid & 63;
  const int wid = tid >> 6;
  const int h0 = tid * 2;

  __shared__ float uLds[kSeq * 4];           // u padded to stride 4 (16 KB)
  __shared__ float wbuf[4][12];              // per-wave partial sums
  __shared__ __align__(16) float fbuf[8];    // final rM[4], rN[4]

  // Stage u for this batch into LDS, padded so per-step read is one b128.
  const float* ub = u + (size_t)b * kSeq * kIn;
  for (int i = tid; i < kSeq * kIn; i += kBlock) {
    int t = i / 3;
    uLds[t * 4 + (i - t * 3)] = ub[i];
  }

  constexpr float inv_h2 = 1.0f / ((float)kHid * (float)kHid);

  // Per-thread weights in registers (h0 even -> all vector loads aligned).
  float4 LA = *(const float4*)&Lw[(size_t)h0 * kRank];
  float4 LB = *(const float4*)&Lw[(size_t)(h0 + 1) * kRank];
  LA.x *= inv_h2; LA.y *= inv_h2; LA.z *= inv_h2; LA.w *= inv_h2;
  LB.x *= inv_h2; LB.y *= inv_h2; LB.z *= inv_h2; LB.w *= inv_h2;
  float4 MA = *(const float4*)&Mw[(size_t)h0 * kRank];
  float4 MB = *(const float4*)&Mw[(size_t)(h0 + 1) * kRank];
  float4 NA = *(const float4*)&Nw[(size_t)h0 * kRank];
  float4 NB = *(const float4*)&Nw[(size_t)(h0 + 1) * kRank];
  float WiA0 = Win[h0 * 3 + 0], WiA1 = Win[h0 * 3 + 1], WiA2 = Win[h0 * 3 + 2];
  float WiB0 = Win[(h0 + 1) * 3 + 0], WiB1 = Win[(h0 + 1) * 3 + 1],
        WiB2 = Win[(h0 + 1) * 3 + 2];
  float2 Wo0 = *(const float2*)&Wout[0 * kHid + h0];
  float2 Wo1 = *(const float2*)&Wout[1 * kHid + h0];
  float2 Wo2 = *(const float2*)&Wout[2 * kHid + h0];
  float2 bs = *(const float2*)&bias[h0];

  float2 xv = *(const float2*)&x0[(size_t)b * kHid + h0];
  float xA = xv.x, xB = xv.y;

  // trajectories[:, 0, :] = x0
  *(float2*)&traj[((size_t)b * (kSeq + 1)) * kHid + h0] = make_float2(xA, xB);

  // r0 = tanh(x0) WITHOUT bias (reference semantics)
  float rA = tanh_fast(xA), rB = tanh_fast(xB);
  float txA = 0.0f, txB = 0.0f;  // pending tanh(x_t) partial inputs (unused at t=0)

  const float* nsb = noise + (size_t)b * kHid + h0;
  float2 n0 = *(const float2*)&nsb[0];
  float2 n1 = *(const float2*)&nsb[(size_t)kBatch * kHid];

  __syncthreads();  // uLds ready

  for (int t = 0; t < kSeq; ++t) {
    // Prefetch noise for t+2 (distance-2 to cover HBM latency).
    int tp = (t + 2 < kSeq) ? t + 2 : kSeq - 1;
    float2 nn = *(const float2*)&nsb[(size_t)tp * kBatch * kHid];

    // 11 reduction partials: rM[4], rN[4] from current r; out row t-1 from tx.
    float pm0 = fmaf(rB, MB.x, rA * MA.x);
    float pm1 = fmaf(rB, MB.y, rA * MA.y);
    float pm2 = fmaf(rB, MB.z, rA * MA.z);
    float pm3 = fmaf(rB, MB.w, rA * MA.w);
    float pn0 = fmaf(rB, NB.x, rA * NA.x);
    float pn1 = fmaf(rB, NB.y, rA * NA.y);
    float pn2 = fmaf(rB, NB.z, rA * NA.z);
    float pn3 = fmaf(rB, NB.w, rA * NA.w);
    float po0 = fmaf(txB, Wo0.y, txA * Wo0.x);
    float po1 = fmaf(txB, Wo1.y, txA * Wo1.x);
    float po2 = fmaf(txB, Wo2.y, txA * Wo2.x);

    pm0 = wave_sum63(pm0); pm1 = wave_sum63(pm1);
    pm2 = wave_sum63(pm2); pm3 = wave_sum63(pm3);
    pn0 = wave_sum63(pn0); pn1 = wave_sum63(pn1);
    pn2 = wave_sum63(pn2); pn3 = wave_sum63(pn3);
    po0 = wave_sum63(po0); po1 = wave_sum63(po1); po2 = wave_sum63(po2);

    if (lane == 63) {
      wbuf[wid][0] = pm0; wbuf[wid][1] = pm1; wbuf[wid][2] = pm2; wbuf[wid][3] = pm3;
      wbuf[wid][4] = pn0; wbuf[wid][5] = pn1; wbuf[wid][6] = pn2; wbuf[wid][7] = pn3;
      wbuf[wid][8] = po0; wbuf[wid][9] = po1; wbuf[wid][10] = po2;
    }
    __syncthreads();
    if (tid < 44) {  // 11 values x 4 wave-partials; quad k handles value k
      int k = tid >> 2, w = tid & 3;
      float v = quad_sum(wbuf[w][k]);
      if (w == 0) {
        if (k < 8) {
          fbuf[k] = v;
        } else if (t > 0) {
          out[(size_t)b * kSeq * kOut + (size_t)(t - 1) * kOut + (k - 8)] = v;
        }
      }
    }
    __syncthreads();

    float4 rm = *(const float4*)&fbuf[0];
    float4 rn = *(const float4*)&fbuf[4];
    float p0 = rm.x * rn.x, p1 = rm.y * rn.y, p2 = rm.z * rn.z, p3 = rm.w * rn.w;

    float4 ut = *(const float4*)&uLds[t * 4];  // u0,u1,u2,(pad)

    float hidA = fmaf(p3, LA.w, fmaf(p2, LA.z, fmaf(p1, LA.y, p0 * LA.x)));
    float hidB = fmaf(p3, LB.w, fmaf(p2, LB.z, fmaf(p1, LB.y, p0 * LB.x)));
    float inA = fmaf(ut.z, WiA2, fmaf(ut.y, WiA1, ut.x * WiA0));
    float inB = fmaf(ut.z, WiB2, fmaf(ut.y, WiB1, ut.x * WiB0));

    xA = xA + kNoiseStd * n0.x + kTau * (-xA + hidA + inA);
    xB = xB + kNoiseStd * n0.y + kTau * (-xB + hidB + inB);

    *(float2*)&traj[((size_t)b * (kSeq + 1) + (t + 1)) * kHid + h0] =
        make_float2(xA, xB);

    rA = tanh_fast(xA + bs.x); rB = tanh_fast(xB + bs.y);
    txA = tanh_fast(xA);       txB = tanh_fast(xB);

    n0 = n1; n1 = nn;
  }

  // Epilogue: output row SEQ-1 from tanh(x_SEQ).
  float po0 = fmaf(txB, Wo0.y, txA * Wo0.x);
  float po1 = fmaf(txB, Wo1.y, txA * Wo1.x);
  float po2 = fmaf(txB, Wo2.y, txA * Wo2.x);
  po0 = wave_sum63(po0); po1 = wave_sum63(po1); po2 = wave_sum63(po2);
  if (lane == 63) {
    wbuf[wid][0] = po0; wbuf[wid][1] = po1; wbuf[wid][2] = po2;
  }
  __syncthreads();
  if (tid < 12) {
    int k = tid >> 2, w = tid & 3;
    float v = quad_sum(wbuf[w][k]);
    if (w == 0) {
      out[(size_t)b * kSeq * kOut + (size_t)(kSeq - 1) * kOut + k] = v;
    }
  }

  *(float2*)&xfinal[(size_t)b * kHid + h0] = make_float2(xA, xB);
}

}  // namespace

extern "C" void kernel_launch(void* const* d_in, const int* in_sizes, int n_in,
                              void* d_out, int out_size, void* d_ws,
                              size_t ws_size, hipStream_t stream) {
  const float* u = (const float*)d_in[0];      // (128, 1000, 3)
  const float* x0 = (const float*)d_in[1];     // (128, 512)
  const float* noise = (const float*)d_in[2];  // (1000, 128, 512)
  const float* Lw = (const float*)d_in[3];     // (512, 4)
  const float* Mw = (const float*)d_in[4];     // (512, 4)
  const float* Nw = (const float*)d_in[5];     // (512, 4)
  const float* bias = (const float*)d_in[6];   // (512,)
  const float* Win = (const float*)d_in[7];    // (512, 3)
  const float* Wout = (const float*)d_in[8];   // (3, 512)

  float* out = (float*)d_out;                       // (128, 1000, 3)
  float* xfinal = out + (size_t)kBatch * kSeq * kOut;          // (128, 512)
  float* traj = xfinal + (size_t)kBatch * kHid;     // (128, 1001, 512)

  rnn_fused<<<dim3(kBatch), dim3(kBlock), 0, stream>>>(
      u, x0, noise, Lw, Mw, Nw, bias, Win, Wout, out, xfinal, traj);
}